// Round 7
// baseline (191.878 us; speedup 1.0000x reference)
//
#include <hip/hip_runtime.h>
#include <hip/hip_bf16.h>

#define NROW 50000
#define DIN 128
#define DM 256
#define HH 4
#define NC 40
#define BHN 200000
#define NBLK 3125   // 50000/16 exact: 16 rows per wave, no bounds checks

typedef float f32x4 __attribute__((ext_vector_type(4)));
typedef short bf16x8 __attribute__((ext_vector_type(8)));

__device__ __forceinline__ unsigned short f2bf(float x) {
    unsigned int u = __float_as_uint(x);
    u += 0x7fffu + ((u >> 16) & 1u);
    return (unsigned short)(u >> 16);
}

__device__ __forceinline__ unsigned int pk2(float lo, float hi) {
    __hip_bfloat162 h = __float22bfloat162_rn(make_float2(lo, hi));
    return *(unsigned int*)&h;
}

__device__ __forceinline__ float bf2f(unsigned short s) {
    return __uint_as_float(((unsigned int)s) << 16);
}

// -------- prep: [0,782) scatter | [782,798) Wpk | [798,810) Wgpk | [810,850) bias2+cs --------
// Wpk  [kc][t][ln][8]: fragment-order packed bf16 of Win^T
// Wgpk [h][kc][t][ln][8]: fragment-order packed bf16 of gamma*Wh^T
__global__ __launch_bounds__(256) void k_prep(const int* __restrict__ pi,
                                              const float* __restrict__ pv,
                                              const float* __restrict__ Win,
                                              const float* __restrict__ Wh,
                                              const float* __restrict__ gamma,
                                              const float* __restrict__ beta,
                                              const float* __restrict__ bh,
                                              float* __restrict__ vcol,
                                              unsigned short* __restrict__ Wpk,
                                              unsigned short* __restrict__ Wgpk,
                                              float* __restrict__ bias2,
                                              float* __restrict__ cs) {
    const int bid = blockIdx.x, tid = threadIdx.x;
    if (bid < 782) {
        int k = bid * 256 + tid;
        if (k < BHN) {
            int b = (k >= 150000) ? 3 : (k >= 100000) ? 2 : (k >= 50000) ? 1 : 0;
            int col = pi[2 * BHN + k];
            vcol[b * NROW + col] = pv[k];
        }
    } else if (bid < 798) {
        int base = (bid - 782) * 512;
        #pragma unroll
        for (int q = 0; q < 2; ++q) {
            int s = base + q * 256 + tid;
            int ln = s & 63;
            int t  = (s >> 6) & 15;
            int kc = s >> 10;
            int n  = t * 16 + (ln & 15);
            int kb = kc * 32 + ((ln >> 4) << 3);
            union { unsigned int ui[4]; uint4 v4; } u;
            #pragma unroll
            for (int jj = 0; jj < 4; ++jj)
                u.ui[jj] = pk2(Win[(kb + 2 * jj) * DM + n], Win[(kb + 2 * jj + 1) * DM + n]);
            *(uint4*)&Wpk[s * 8] = u.v4;
        }
    } else if (bid < 810) {
        int base = (bid - 798) * 512;
        #pragma unroll
        for (int q = 0; q < 2; ++q) {
            int s = base + q * 256 + tid;
            int ln = s & 63;
            int u6 = s >> 6;
            int t  = u6 % 3;
            int v6 = u6 / 3;
            int kc = v6 & 7;
            int h  = v6 >> 3;
            int c  = t * 16 + (ln & 15);
            int d0 = h * 256 + kc * 32 + ((ln >> 4) << 3);
            union { unsigned int ui[4]; uint4 v4; } u;
            if (c < NC) {
                #pragma unroll
                for (int jj = 0; jj < 4; ++jj)
                    u.ui[jj] = pk2(gamma[d0 + 2 * jj] * Wh[(d0 + 2 * jj) * NC + c],
                                   gamma[d0 + 2 * jj + 1] * Wh[(d0 + 2 * jj + 1) * NC + c]);
            } else {
                u.v4 = make_uint4(0u, 0u, 0u, 0u);
            }
            *(uint4*)&Wgpk[s * 8] = u.v4;
        }
    } else {   // bias2[c] = bh[c] + sum_d beta[d]*Wh[d][c]; cs[c] = sum_d gamma[d]*Wh[d][c]
        __shared__ float red[256], red2[256];
        int c = bid - 810;
        float sb = 0.f, sc = 0.f;
        #pragma unroll
        for (int q = 0; q < 4; ++q) {
            int d = tid + 256 * q;
            float w = Wh[d * NC + c];
            sb = fmaf(beta[d], w, sb);
            sc = fmaf(gamma[d], w, sc);
        }
        red[tid] = sb; red2[tid] = sc;
        __syncthreads();
        for (int st = 128; st > 0; st >>= 1) {
            if (tid < st) { red[tid] += red[tid + st]; red2[tid] += red2[tid + st]; }
            __syncthreads();
        }
        if (tid == 0) { bias2[c] = bh[c] + red[0]; cs[c] = red2[0]; }
    }
}

// -------- fused: 16 rows/wave (grid 3125 -> ~12 waves/CU), no spill, affine-LN epilogue --------
__global__ __launch_bounds__(64, 3) void k_fused(
    const float* __restrict__ feats, const float* __restrict__ appd,
    const unsigned short* __restrict__ Wpk,
    const unsigned short* __restrict__ Wgpk,
    const float* __restrict__ vcol,
    const float* __restrict__ b_in,
    const float* __restrict__ bias2,
    const float* __restrict__ cs,
    float* __restrict__ out)
{
    __shared__ __align__(16) unsigned short Gb[16 * 264];
    __shared__ float rsS[16], rmS[16];

    const int tid = threadIdx.x;
    const int quad = tid >> 4;
    const int lr = tid & 15;
    const int j0 = blockIdx.x * 16;
    const int ar = j0 + lr;              // A-frag row (exact, no clamp)

    const f32x4 zero4 = {0.f, 0.f, 0.f, 0.f};

    // ---- phase 1: G[16][256] = A @ W_in; accG = 64 regs ----
    f32x4 accG[16];
    #pragma unroll
    for (int t = 0; t < 16; ++t) accG[t] = zero4;

    #pragma unroll
    for (int kc = 0; kc < 8; ++kc) {
        const float* src = (kc < 4) ? feats : appd;
        const int ko = (kc & 3) * 32 + quad * 8;
        float4 x0 = *(const float4*)&src[(size_t)ar * DIN + ko];
        float4 x1 = *(const float4*)&src[(size_t)ar * DIN + ko + 4];
        union { unsigned int ui[4]; bf16x8 v; } a;
        a.ui[0] = pk2(x0.x, x0.y); a.ui[1] = pk2(x0.z, x0.w);
        a.ui[2] = pk2(x1.x, x1.y); a.ui[3] = pk2(x1.z, x1.w);
        #pragma unroll
        for (int t = 0; t < 16; ++t) {
            bf16x8 bf = *(const bf16x8*)&Wpk[(size_t)(((kc * 16 + t) << 6) + tid) * 8];
            accG[t] = __builtin_amdgcn_mfma_f32_16x16x32_bf16(a.v, bf, accG[t], 0, 0, 0);
        }
    }

    // ---- phase 2: spill G to LDS (bf16) + LN stats; accG dies here ----
    float vhh[HH][4];   // v at C-layout rows quad*4+rg (lives to epilogue)
    #pragma unroll
    for (int h = 0; h < HH; ++h)
        #pragma unroll
        for (int rg = 0; rg < 4; ++rg)
            vhh[h][rg] = vcol[h * NROW + j0 + quad * 4 + rg];

    float s_[4] = {0.f, 0.f, 0.f, 0.f}, ss_[4] = {0.f, 0.f, 0.f, 0.f};
    #pragma unroll
    for (int t = 0; t < 16; ++t) {
        float bt = b_in[t * 16 + lr];
        #pragma unroll
        for (int rg = 0; rg < 4; ++rg) {
            float gg = accG[t][rg];
            Gb[(quad * 4 + rg) * 264 + t * 16 + lr] = f2bf(gg);
            #pragma unroll
            for (int h = 0; h < HH; ++h) {
                float v = vhh[h][rg];
                float y = v * fmaxf(fmaf(v, gg, bt), 0.f);
                s_[rg] += y;
                ss_[rg] = fmaf(y, y, ss_[rg]);
            }
        }
    }
    #pragma unroll
    for (int m = 1; m <= 8; m <<= 1)
        #pragma unroll
        for (int rg = 0; rg < 4; ++rg) {
            s_[rg] += __shfl_xor(s_[rg], m);
            ss_[rg] += __shfl_xor(ss_[rg], m);
        }
    if (lr == 0) {
        #pragma unroll
        for (int rg = 0; rg < 4; ++rg) {
            float mm = s_[rg] * (1.f / 1024.f);
            float var = ss_[rg] * (1.f / 1024.f) - mm * mm;
            float r_ = rsqrtf(var + 1e-5f);
            rsS[quad * 4 + rg] = r_;
            rmS[quad * 4 + rg] = r_ * mm;
        }
    }
    __syncthreads();

    // ---- phase 3: h outer; accP[3] per head folded into accT[3] by v_h (no big arrays) ----
    f32x4 accT[3];
    #pragma unroll
    for (int t = 0; t < 3; ++t) accT[t] = zero4;

    #pragma unroll
    for (int h = 0; h < HH; ++h) {
        const float vmh = vcol[h * NROW + ar];   // v at A-frag row
        f32x4 accP[3];
        #pragma unroll
        for (int t = 0; t < 3; ++t) accP[t] = zero4;
        #pragma unroll
        for (int kc = 0; kc < 8; ++kc) {
            bf16x8 gf = *(const bf16x8*)&Gb[lr * 264 + kc * 32 + quad * 8];
            float4 bA = *(const float4*)&b_in[kc * 32 + quad * 8];
            float4 bB = *(const float4*)&b_in[kc * 32 + quad * 8 + 4];
            float bb[8] = {bA.x, bA.y, bA.z, bA.w, bB.x, bB.y, bB.z, bB.w};
            union { unsigned int ui[4]; bf16x8 v; } u;
            #pragma unroll
            for (int jj = 0; jj < 4; ++jj) {
                float ya = fmaxf(fmaf(vmh, bf2f((unsigned short)gf[2 * jj]), bb[2 * jj]), 0.f);
                float yb = fmaxf(fmaf(vmh, bf2f((unsigned short)gf[2 * jj + 1]), bb[2 * jj + 1]), 0.f);
                u.ui[jj] = pk2(ya, yb);
            }
            #pragma unroll
            for (int t = 0; t < 3; ++t) {
                bf16x8 wf = *(const bf16x8*)&Wgpk[(size_t)((((h * 8 + kc) * 3 + t) << 6) + tid) * 8];
                accP[t] = __builtin_amdgcn_mfma_f32_16x16x32_bf16(u.v, wf, accP[t], 0, 0, 0);
            }
        }
        #pragma unroll
        for (int t = 0; t < 3; ++t)
            #pragma unroll
            for (int rg = 0; rg < 4; ++rg)
                accT[t][rg] = fmaf(vhh[h][rg], accP[t][rg], accT[t][rg]);
    }

    // ---- epilogue: out = rs*accT - rs*mu*cs + bias2 ----
    #pragma unroll
    for (int t = 0; t < 3; ++t) {
        int c = t * 16 + lr;
        if (c < NC) {
            float ct = cs[c];
            float b2 = bias2[c];
            #pragma unroll
            for (int rg = 0; rg < 4; ++rg) {
                int rr = quad * 4 + rg;
                float base = fmaf(-rmS[rr], ct, b2);
                out[(size_t)(j0 + rr) * NC + c] = fmaf(rsS[rr], accT[t][rg], base);
            }
        }
    }
}

extern "C" void kernel_launch(void* const* d_in, const int* in_sizes, int n_in,
                              void* d_out, int out_size, void* d_ws, size_t ws_size,
                              hipStream_t stream) {
    const int*   pi    = (const int*)d_in[0];
    const float* pv    = (const float*)d_in[1];
    const float* feats = (const float*)d_in[2];
    const float* appd  = (const float*)d_in[3];
    const float* Win   = (const float*)d_in[4];
    const float* b_in  = (const float*)d_in[5];
    const float* gamma = (const float*)d_in[6];
    const float* beta  = (const float*)d_in[7];
    const float* Wh    = (const float*)d_in[8];
    const float* bh    = (const float*)d_in[9];
    float* out = (float*)d_out;

    char* w = (char*)d_ws;
    float*          vcolW  = (float*)w;                        // 800000 B
    unsigned short* WpkW   = (unsigned short*)(w + 800000);    // 131072 B
    unsigned short* WgpkW  = (unsigned short*)(w + 931072);    // 98304 B
    float*          bias2W = (float*)(w + 1029376);            // 160 B
    float*          csW    = (float*)(w + 1029536);            // 160 B

    k_prep<<<850, 256, 0, stream>>>(pi, pv, Win, Wh, gamma, beta, bh, vcolW, WpkW, WgpkW, bias2W, csW);
    k_fused<<<NBLK, 64, 0, stream>>>(feats, appd, WpkW, WgpkW, vcolW, b_in, bias2W, csW, out);
}

// Round 8
// 148.137 us; speedup vs baseline: 1.2953x; 1.2953x over previous
//
#include <hip/hip_runtime.h>
#include <hip/hip_bf16.h>

#define NROW 50000
#define DIN 128
#define DM 256
#define HH 4
#define NC 40
#define BHN 200000
#define NBLK 3125   // 50000/16 exact: 16 rows per wave

typedef float f32x4 __attribute__((ext_vector_type(4)));
typedef short bf16x8 __attribute__((ext_vector_type(8)));

__device__ __forceinline__ unsigned short f2bf(float x) {
    unsigned int u = __float_as_uint(x);
    u += 0x7fffu + ((u >> 16) & 1u);
    return (unsigned short)(u >> 16);
}

__device__ __forceinline__ unsigned int pk2(float lo, float hi) {
    __hip_bfloat162 h = __float22bfloat162_rn(make_float2(lo, hi));
    return *(unsigned int*)&h;
}

__device__ __forceinline__ float bf2f(unsigned short s) {
    return __uint_as_float(((unsigned int)s) << 16);
}

// -------- prep: [0,782) scatter | [782,798) Wpk | [798,810) Wgpk | [810,850) bias2 --------
// Wpk  [kc][t][ln][8]: fragment-order packed bf16 of Win^T
// Wgpk [h][kc][t][ln][8]: fragment-order packed bf16 of gamma*Wh^T (zero-padded c>=40)
__global__ __launch_bounds__(256) void k_prep(const int* __restrict__ pi,
                                              const float* __restrict__ pv,
                                              const float* __restrict__ Win,
                                              const float* __restrict__ Wh,
                                              const float* __restrict__ gamma,
                                              const float* __restrict__ beta,
                                              const float* __restrict__ bh,
                                              float* __restrict__ vcol,
                                              unsigned short* __restrict__ Wpk,
                                              unsigned short* __restrict__ Wgpk,
                                              float* __restrict__ bias2) {
    const int bid = blockIdx.x, tid = threadIdx.x;
    if (bid < 782) {
        int k = bid * 256 + tid;
        if (k < BHN) {
            int b = (k >= 150000) ? 3 : (k >= 100000) ? 2 : (k >= 50000) ? 1 : 0;
            int col = pi[2 * BHN + k];
            vcol[b * NROW + col] = pv[k];
        }
    } else if (bid < 798) {
        int base = (bid - 782) * 512;
        #pragma unroll
        for (int q = 0; q < 2; ++q) {
            int s = base + q * 256 + tid;
            int ln = s & 63;
            int t  = (s >> 6) & 15;
            int kc = s >> 10;
            int n  = t * 16 + (ln & 15);
            int kb = kc * 32 + ((ln >> 4) << 3);
            union { unsigned int ui[4]; uint4 v4; } u;
            #pragma unroll
            for (int jj = 0; jj < 4; ++jj)
                u.ui[jj] = pk2(Win[(kb + 2 * jj) * DM + n], Win[(kb + 2 * jj + 1) * DM + n]);
            *(uint4*)&Wpk[s * 8] = u.v4;
        }
    } else if (bid < 810) {
        int base = (bid - 798) * 512;
        #pragma unroll
        for (int q = 0; q < 2; ++q) {
            int s = base + q * 256 + tid;
            int ln = s & 63;
            int u6 = s >> 6;
            int t  = u6 % 3;
            int v6 = u6 / 3;
            int kc = v6 & 7;
            int h  = v6 >> 3;
            int c  = t * 16 + (ln & 15);
            int d0 = h * 256 + kc * 32 + ((ln >> 4) << 3);
            union { unsigned int ui[4]; uint4 v4; } u;
            if (c < NC) {
                #pragma unroll
                for (int jj = 0; jj < 4; ++jj)
                    u.ui[jj] = pk2(gamma[d0 + 2 * jj] * Wh[(d0 + 2 * jj) * NC + c],
                                   gamma[d0 + 2 * jj + 1] * Wh[(d0 + 2 * jj + 1) * NC + c]);
            } else {
                u.v4 = make_uint4(0u, 0u, 0u, 0u);
            }
            *(uint4*)&Wgpk[s * 8] = u.v4;
        }
    } else {   // bias2[c] = bh[c] + sum_d beta[d]*Wh[d][c]
        __shared__ float red[256];
        int c = bid - 810;
        float sb = 0.f;
        #pragma unroll
        for (int q = 0; q < 4; ++q) {
            int d = tid + 256 * q;
            sb = fmaf(beta[d], Wh[d * NC + c], sb);
        }
        red[tid] = sb;
        __syncthreads();
        for (int st = 128; st > 0; st >>= 1) {
            if (tid < st) red[tid] += red[tid + st];
            __syncthreads();
        }
        if (tid == 0) bias2[c] = bh[c] + red[0];
    }
}

// -------- fused: R4 shape (16 rows/wave, in-loop normalize) + packed coalesced weights --------
__global__ __launch_bounds__(64, 3) void k_fused(
    const float* __restrict__ feats, const float* __restrict__ appd,
    const unsigned short* __restrict__ Wpk,
    const unsigned short* __restrict__ Wgpk,
    const float* __restrict__ vcol,
    const float* __restrict__ b_in,
    const float* __restrict__ bias2,
    float* __restrict__ out)
{
    __shared__ __align__(16) unsigned short Gb[16 * 264];
    __shared__ float rsS[16], nmS[16];

    const int tid = threadIdx.x;
    const int quad = tid >> 4;
    const int lr = tid & 15;
    const int j0 = blockIdx.x * 16;
    const int ar = j0 + lr;

    const f32x4 zero4 = {0.f, 0.f, 0.f, 0.f};

    // ---- phase 1: G[16][256] = A @ W_in; kc NOT unrolled (limits load hoisting) ----
    f32x4 accG[16];
    #pragma unroll
    for (int t = 0; t < 16; ++t) accG[t] = zero4;

    #pragma unroll 1
    for (int kc = 0; kc < 8; ++kc) {
        const float* src = (kc < 4) ? feats : appd;
        const int ko = (kc & 3) * 32 + quad * 8;
        float4 x0 = *(const float4*)&src[(size_t)ar * DIN + ko];
        float4 x1 = *(const float4*)&src[(size_t)ar * DIN + ko + 4];
        union { unsigned int ui[4]; bf16x8 v; } a;
        a.ui[0] = pk2(x0.x, x0.y); a.ui[1] = pk2(x0.z, x0.w);
        a.ui[2] = pk2(x1.x, x1.y); a.ui[3] = pk2(x1.z, x1.w);
        #pragma unroll
        for (int t = 0; t < 16; ++t) {
            bf16x8 bf = *(const bf16x8*)&Wpk[(size_t)(((kc * 16 + t) << 6) + tid) * 8];
            accG[t] = __builtin_amdgcn_mfma_f32_16x16x32_bf16(a.v, bf, accG[t], 0, 0, 0);
        }
    }

    // ---- phase 2: spill G to LDS (bf16) + LN stats; accG dies here ----
    float vhh[HH][4];
    #pragma unroll
    for (int h = 0; h < HH; ++h)
        #pragma unroll
        for (int rg = 0; rg < 4; ++rg)
            vhh[h][rg] = vcol[h * NROW + j0 + quad * 4 + rg];

    float s_[4] = {0.f, 0.f, 0.f, 0.f}, ss_[4] = {0.f, 0.f, 0.f, 0.f};
    #pragma unroll
    for (int t = 0; t < 16; ++t) {
        float bt = b_in[t * 16 + lr];
        #pragma unroll
        for (int rg = 0; rg < 4; ++rg) {
            float gg = accG[t][rg];
            Gb[(quad * 4 + rg) * 264 + t * 16 + lr] = f2bf(gg);
            #pragma unroll
            for (int h = 0; h < HH; ++h) {
                float v = vhh[h][rg];
                float y = v * fmaxf(fmaf(v, gg, bt), 0.f);
                s_[rg] += y;
                ss_[rg] = fmaf(y, y, ss_[rg]);
            }
        }
    }
    #pragma unroll
    for (int m = 1; m <= 8; m <<= 1)
        #pragma unroll
        for (int rg = 0; rg < 4; ++rg) {
            s_[rg] += __shfl_xor(s_[rg], m);
            ss_[rg] += __shfl_xor(ss_[rg], m);
        }
    if (lr == 0) {
        #pragma unroll
        for (int rg = 0; rg < 4; ++rg) {
            float mm = s_[rg] * (1.f / 1024.f);
            float var = ss_[rg] * (1.f / 1024.f) - mm * mm;
            float r_ = rsqrtf(var + 1e-5f);
            rsS[quad * 4 + rg] = r_;
            nmS[quad * 4 + rg] = -mm * r_;
        }
    }
    __syncthreads();

    // ---- phase 3: per-lane A-row lr; z = (v*relu(v*g+b))*rs + nm in-loop; single accO ----
    float vm[HH];
    #pragma unroll
    for (int h = 0; h < HH; ++h) vm[h] = vcol[h * NROW + ar];
    const float rsm = rsS[lr], nmm = nmS[lr];

    f32x4 accO[3];
    #pragma unroll
    for (int t = 0; t < 3; ++t) accO[t] = zero4;

    #pragma unroll 1
    for (int kc = 0; kc < 8; ++kc) {
        bf16x8 gf = *(const bf16x8*)&Gb[lr * 264 + kc * 32 + quad * 8];
        float4 bA = *(const float4*)&b_in[kc * 32 + quad * 8];
        float4 bB = *(const float4*)&b_in[kc * 32 + quad * 8 + 4];
        float bb[8] = {bA.x, bA.y, bA.z, bA.w, bB.x, bB.y, bB.z, bB.w};
        float g[8];
        #pragma unroll
        for (int j = 0; j < 8; ++j) g[j] = bf2f((unsigned short)gf[j]);
        #pragma unroll
        for (int h = 0; h < HH; ++h) {
            union { unsigned int ui[4]; bf16x8 v; } u;
            #pragma unroll
            for (int jj = 0; jj < 4; ++jj) {
                float ya = vm[h] * fmaxf(fmaf(vm[h], g[2 * jj], bb[2 * jj]), 0.f);
                float yb = vm[h] * fmaxf(fmaf(vm[h], g[2 * jj + 1], bb[2 * jj + 1]), 0.f);
                u.ui[jj] = pk2(fmaf(ya, rsm, nmm), fmaf(yb, rsm, nmm));
            }
            #pragma unroll
            for (int t = 0; t < 3; ++t) {
                bf16x8 wf = *(const bf16x8*)&Wgpk[(size_t)((((h * 8 + kc) * 3 + t) << 6) + tid) * 8];
                accO[t] = __builtin_amdgcn_mfma_f32_16x16x32_bf16(u.v, wf, accO[t], 0, 0, 0);
            }
        }
    }

    // ---- epilogue ----
    #pragma unroll
    for (int t = 0; t < 3; ++t) {
        int c = t * 16 + lr;
        if (c < NC) {
            float b2 = bias2[c];
            #pragma unroll
            for (int rg = 0; rg < 4; ++rg) {
                int row = j0 + quad * 4 + rg;
                out[(size_t)row * NC + c] = accO[t][rg] + b2;
            }
        }
    }
}

extern "C" void kernel_launch(void* const* d_in, const int* in_sizes, int n_in,
                              void* d_out, int out_size, void* d_ws, size_t ws_size,
                              hipStream_t stream) {
    const int*   pi    = (const int*)d_in[0];
    const float* pv    = (const float*)d_in[1];
    const float* feats = (const float*)d_in[2];
    const float* appd  = (const float*)d_in[3];
    const float* Win   = (const float*)d_in[4];
    const float* b_in  = (const float*)d_in[5];
    const float* gamma = (const float*)d_in[6];
    const float* beta  = (const float*)d_in[7];
    const float* Wh    = (const float*)d_in[8];
    const float* bh    = (const float*)d_in[9];
    float* out = (float*)d_out;

    char* w = (char*)d_ws;
    float*          vcolW  = (float*)w;                        // 800000 B
    unsigned short* WpkW   = (unsigned short*)(w + 800000);    // 131072 B
    unsigned short* WgpkW  = (unsigned short*)(w + 931072);    // 98304 B
    float*          bias2W = (float*)(w + 1029376);            // 160 B

    k_prep<<<850, 256, 0, stream>>>(pi, pv, Win, Wh, gamma, beta, bh, vcolW, WpkW, WgpkW, bias2W);
    k_fused<<<NBLK, 64, 0, stream>>>(feats, appd, WpkW, WgpkW, vcolW, b_in, bias2W, out);
}

// Round 9
// 143.686 us; speedup vs baseline: 1.3354x; 1.0310x over previous
//
#include <hip/hip_runtime.h>
#include <hip/hip_bf16.h>

#define NROW 50000
#define DIN 128
#define DM 256
#define HH 4
#define NC 40
#define BHN 200000
#define NBLK 782   // ceil(50000/64): 64 rows per 4-wave block

typedef float f32x4 __attribute__((ext_vector_type(4)));
typedef short bf16x8 __attribute__((ext_vector_type(8)));

__device__ __forceinline__ unsigned short f2bf(float x) {
    unsigned int u = __float_as_uint(x);
    u += 0x7fffu + ((u >> 16) & 1u);
    return (unsigned short)(u >> 16);
}

__device__ __forceinline__ unsigned int pk2(float lo, float hi) {
    __hip_bfloat162 h = __float22bfloat162_rn(make_float2(lo, hi));
    return *(unsigned int*)&h;
}

__device__ __forceinline__ float bf2f(unsigned short s) {
    return __uint_as_float(((unsigned int)s) << 16);
}

// async 16B/lane global->LDS: lds dest = base + lane*16
__device__ __forceinline__ void gl_lds16(const unsigned short* g, unsigned short* l) {
    __builtin_amdgcn_global_load_lds(
        (const __attribute__((address_space(1))) unsigned int*)(g),
        (__attribute__((address_space(3))) unsigned int*)(l),
        16, 0, 0);
}

// -------- prep: [0,782) scatter | [782,798) Wpk | [798,810) Wgpk | [810,850) bias2 --------
// Wpk  [kc][t][ln][8]: fragment-order packed bf16 of Win^T
// Wgpk [h][kc][t][ln][8]: fragment-order packed bf16 of gamma*Wh^T (zero-padded c>=40)
__global__ __launch_bounds__(256) void k_prep(const int* __restrict__ pi,
                                              const float* __restrict__ pv,
                                              const float* __restrict__ Win,
                                              const float* __restrict__ Wh,
                                              const float* __restrict__ gamma,
                                              const float* __restrict__ beta,
                                              const float* __restrict__ bh,
                                              float* __restrict__ vcol,
                                              unsigned short* __restrict__ Wpk,
                                              unsigned short* __restrict__ Wgpk,
                                              float* __restrict__ bias2) {
    const int bid = blockIdx.x, tid = threadIdx.x;
    if (bid < 782) {
        int k = bid * 256 + tid;
        if (k < BHN) {
            int b = (k >= 150000) ? 3 : (k >= 100000) ? 2 : (k >= 50000) ? 1 : 0;
            int col = pi[2 * BHN + k];
            vcol[b * NROW + col] = pv[k];
        }
    } else if (bid < 798) {
        int base = (bid - 782) * 512;
        #pragma unroll
        for (int q = 0; q < 2; ++q) {
            int s = base + q * 256 + tid;
            int ln = s & 63;
            int t  = (s >> 6) & 15;
            int kc = s >> 10;
            int n  = t * 16 + (ln & 15);
            int kb = kc * 32 + ((ln >> 4) << 3);
            union { unsigned int ui[4]; uint4 v4; } u;
            #pragma unroll
            for (int jj = 0; jj < 4; ++jj)
                u.ui[jj] = pk2(Win[(kb + 2 * jj) * DM + n], Win[(kb + 2 * jj + 1) * DM + n]);
            *(uint4*)&Wpk[s * 8] = u.v4;
        }
    } else if (bid < 810) {
        int base = (bid - 798) * 512;
        #pragma unroll
        for (int q = 0; q < 2; ++q) {
            int s = base + q * 256 + tid;
            int ln = s & 63;
            int u6 = s >> 6;
            int t  = u6 % 3;
            int v6 = u6 / 3;
            int kc = v6 & 7;
            int h  = v6 >> 3;
            int c  = t * 16 + (ln & 15);
            int d0 = h * 256 + kc * 32 + ((ln >> 4) << 3);
            union { unsigned int ui[4]; uint4 v4; } u;
            if (c < NC) {
                #pragma unroll
                for (int jj = 0; jj < 4; ++jj)
                    u.ui[jj] = pk2(gamma[d0 + 2 * jj] * Wh[(d0 + 2 * jj) * NC + c],
                                   gamma[d0 + 2 * jj + 1] * Wh[(d0 + 2 * jj + 1) * NC + c]);
            } else {
                u.v4 = make_uint4(0u, 0u, 0u, 0u);
            }
            *(uint4*)&Wgpk[s * 8] = u.v4;
        }
    } else {   // bias2[c] = bh[c] + sum_d beta[d]*Wh[d][c]
        __shared__ float red[256];
        int c = bid - 810;
        float sb = 0.f;
        #pragma unroll
        for (int q = 0; q < 4; ++q) {
            int d = tid + 256 * q;
            sb = fmaf(beta[d], Wh[d * NC + c], sb);
        }
        red[tid] = sb;
        __syncthreads();
        for (int st = 128; st > 0; st >>= 1) {
            if (tid < st) red[tid] += red[tid + st];
            __syncthreads();
        }
        if (tid == 0) bias2[c] = bh[c] + red[0];
    }
}

// -------- fused: 4 waves/block, 16 rows/wave; weights LDS-shared via global_load_lds --------
__global__ __launch_bounds__(256, 3) void k_fused(
    const float* __restrict__ feats, const float* __restrict__ appd,
    const unsigned short* __restrict__ Wpk,
    const unsigned short* __restrict__ Wgpk,
    const float* __restrict__ vcol,
    const float* __restrict__ b_in,
    const float* __restrict__ bias2,
    float* __restrict__ out)
{
    __shared__ __align__(16) unsigned short stage[8192];        // 16 KB weight staging
    __shared__ __align__(16) unsigned short Gb[4][16 * 264];    // per-wave G slice
    __shared__ float rsS[4][16], nmS[4][16];

    const int tid = threadIdx.x;
    const int wv = tid >> 6;
    const int ln = tid & 63;
    const int quad = ln >> 4;
    const int lr = ln & 15;
    const int j0 = blockIdx.x * 64;
    const int jw = j0 + wv * 16;
    const int ar = min(jw + lr, NROW - 1);

    const f32x4 zero4 = {0.f, 0.f, 0.f, 0.f};

    // ---- phase 1: G[16][256] per wave; Wpk chunks staged per block ----
    f32x4 accG[16];
    #pragma unroll
    for (int t = 0; t < 16; ++t) accG[t] = zero4;

    // A prefetch (kc=0)
    float4 x0 = *(const float4*)&feats[(size_t)ar * DIN + quad * 8];
    float4 x1 = *(const float4*)&feats[(size_t)ar * DIN + quad * 8 + 4];

    #pragma unroll 1
    for (int kc = 0; kc < 8; ++kc) {
        __syncthreads();   // previous chunk's LDS reads done
        #pragma unroll
        for (int q = 0; q < 4; ++q) {
            int f = wv * 4 + q;
            gl_lds16(Wpk + ((size_t)((kc * 16 + f) * 64 + ln)) * 8, &stage[f * 512]);
        }
        __syncthreads();   // staging complete (vmcnt drained by barrier)

        union { unsigned int ui[4]; bf16x8 v; } a;
        a.ui[0] = pk2(x0.x, x0.y); a.ui[1] = pk2(x0.z, x0.w);
        a.ui[2] = pk2(x1.x, x1.y); a.ui[3] = pk2(x1.z, x1.w);
        if (kc < 7) {
            const float* srcn = (kc + 1 < 4) ? feats : appd;
            const int kon = ((kc + 1) & 3) * 32 + quad * 8;
            x0 = *(const float4*)&srcn[(size_t)ar * DIN + kon];
            x1 = *(const float4*)&srcn[(size_t)ar * DIN + kon + 4];
        }
        #pragma unroll
        for (int t = 0; t < 16; ++t) {
            bf16x8 bf = *(const bf16x8*)&stage[(t * 64 + ln) * 8];
            accG[t] = __builtin_amdgcn_mfma_f32_16x16x32_bf16(a.v, bf, accG[t], 0, 0, 0);
        }
    }

    // ---- phase 2: spill G to wave-private LDS slice + LN stats ----
    float vhh[HH][4];
    #pragma unroll
    for (int h = 0; h < HH; ++h)
        #pragma unroll
        for (int rg = 0; rg < 4; ++rg)
            vhh[h][rg] = vcol[h * NROW + min(jw + quad * 4 + rg, NROW - 1)];

    float s_[4] = {0.f, 0.f, 0.f, 0.f}, ss_[4] = {0.f, 0.f, 0.f, 0.f};
    #pragma unroll
    for (int t = 0; t < 16; ++t) {
        float bt = b_in[t * 16 + lr];
        #pragma unroll
        for (int rg = 0; rg < 4; ++rg) {
            float gg = accG[t][rg];
            Gb[wv][(quad * 4 + rg) * 264 + t * 16 + lr] = f2bf(gg);
            #pragma unroll
            for (int h = 0; h < HH; ++h) {
                float v = vhh[h][rg];
                float y = v * fmaxf(fmaf(v, gg, bt), 0.f);
                s_[rg] += y;
                ss_[rg] = fmaf(y, y, ss_[rg]);
            }
        }
    }
    #pragma unroll
    for (int m = 1; m <= 8; m <<= 1)
        #pragma unroll
        for (int rg = 0; rg < 4; ++rg) {
            s_[rg] += __shfl_xor(s_[rg], m);
            ss_[rg] += __shfl_xor(ss_[rg], m);
        }
    if (lr == 0) {
        #pragma unroll
        for (int rg = 0; rg < 4; ++rg) {
            float mm = s_[rg] * (1.f / 1024.f);
            float var = ss_[rg] * (1.f / 1024.f) - mm * mm;
            float r_ = rsqrtf(var + 1e-5f);
            rsS[wv][quad * 4 + rg] = r_;
            nmS[wv][quad * 4 + rg] = -mm * r_;
        }
    }
    __syncthreads();   // stats visible; stage buffer free for phase 3

    // ---- phase 3: 8 chunks of (h, kc-half); Wgpk staged per block; accO single ----
    float vm[HH];
    #pragma unroll
    for (int h = 0; h < HH; ++h) vm[h] = vcol[h * NROW + ar];
    const float rsm = rsS[wv][lr], nmm = nmS[wv][lr];

    f32x4 accO[3];
    #pragma unroll
    for (int t = 0; t < 3; ++t) accO[t] = zero4;

    #pragma unroll 1
    for (int ch = 0; ch < 8; ++ch) {
        const int h = ch >> 1;
        const int k0 = (ch & 1) * 4;
        // wave wv stages the 3 frags of kc=k0+wv (12 slots total)
        #pragma unroll
        for (int q = 0; q < 3; ++q) {
            int s = wv * 3 + q;
            gl_lds16(Wgpk + ((size_t)((((h * 8 + k0 + wv) * 3 + q)) * 64 + ln)) * 8,
                     &stage[s * 512]);
        }
        __syncthreads();   // staging complete
        #pragma unroll
        for (int kcr = 0; kcr < 4; ++kcr) {
            const int kc = k0 + kcr;
            bf16x8 gf = *(const bf16x8*)&Gb[wv][lr * 264 + kc * 32 + quad * 8];
            float4 bA = *(const float4*)&b_in[kc * 32 + quad * 8];
            float4 bB = *(const float4*)&b_in[kc * 32 + quad * 8 + 4];
            float bb[8] = {bA.x, bA.y, bA.z, bA.w, bB.x, bB.y, bB.z, bB.w};
            union { unsigned int ui[4]; bf16x8 v; } u;
            #pragma unroll
            for (int jj = 0; jj < 4; ++jj) {
                float ya = vm[h] * fmaxf(fmaf(vm[h], bf2f((unsigned short)gf[2 * jj]), bb[2 * jj]), 0.f);
                float yb = vm[h] * fmaxf(fmaf(vm[h], bf2f((unsigned short)gf[2 * jj + 1]), bb[2 * jj + 1]), 0.f);
                u.ui[jj] = pk2(fmaf(ya, rsm, nmm), fmaf(yb, rsm, nmm));
            }
            #pragma unroll
            for (int t = 0; t < 3; ++t) {
                bf16x8 wf = *(const bf16x8*)&stage[((kcr * 3 + t) * 64 + ln) * 8];
                accO[t] = __builtin_amdgcn_mfma_f32_16x16x32_bf16(u.v, wf, accO[t], 0, 0, 0);
            }
        }
        __syncthreads();   // all reads of this chunk done before restaging
    }

    // ---- epilogue ----
    #pragma unroll
    for (int t = 0; t < 3; ++t) {
        int c = t * 16 + lr;
        if (c < NC) {
            float b2 = bias2[c];
            #pragma unroll
            for (int rg = 0; rg < 4; ++rg) {
                int row = jw + quad * 4 + rg;
                if (row < NROW)
                    out[(size_t)row * NC + c] = accO[t][rg] + b2;
            }
        }
    }
}

extern "C" void kernel_launch(void* const* d_in, const int* in_sizes, int n_in,
                              void* d_out, int out_size, void* d_ws, size_t ws_size,
                              hipStream_t stream) {
    const int*   pi    = (const int*)d_in[0];
    const float* pv    = (const float*)d_in[1];
    const float* feats = (const float*)d_in[2];
    const float* appd  = (const float*)d_in[3];
    const float* Win   = (const float*)d_in[4];
    const float* b_in  = (const float*)d_in[5];
    const float* gamma = (const float*)d_in[6];
    const float* beta  = (const float*)d_in[7];
    const float* Wh    = (const float*)d_in[8];
    const float* bh    = (const float*)d_in[9];
    float* out = (float*)d_out;

    char* w = (char*)d_ws;
    float*          vcolW  = (float*)w;                        // 800000 B
    unsigned short* WpkW   = (unsigned short*)(w + 800000);    // 131072 B
    unsigned short* WgpkW  = (unsigned short*)(w + 931072);    // 98304 B
    float*          bias2W = (float*)(w + 1029376);            // 160 B

    k_prep<<<850, 256, 0, stream>>>(pi, pv, Win, Wh, gamma, beta, bh, vcolW, WpkW, WgpkW, bias2W);
    k_fused<<<NBLK, 256, 0, stream>>>(feats, appd, WpkW, WgpkW, vcolW, b_in, bias2W, out);
}